// Round 8
// baseline (283.904 us; speedup 1.0000x reference)
//
#include <hip/hip_runtime.h>

// AttributeDecoder: out[k,s,:] = feats[mask_idx[k,s],:] @ W[k] + b[k]. fp32.
// R10: barrier-free dense GEMM.
//  R8/R9 post-mortem: mkd pinned at ~90us with ALL pipes idle; structure had
//  12 __syncthreads per block (B double-buffer), each draining vmcnt(0)
//  including the 4 just-issued HBM stores (~600-900cy x 12 x every wave),
//  with only ~3 blocks/CU to overlap. Fix: invert the staging.
//   - A (32 rows of feats) staged ONCE per block into LDS as pre-converted
//     bf16 hi/lo planes (2x16KB, XOR-swizzle byte^=(row&7)<<4 on both sides).
//   - ONE barrier total. Then wave w owns head-pair hp=(bid%3)*4+w with its
//     B-fragments register-resident (64 VGPR, asm-pinned): no further sync,
//     stores never meet a barrier drain.
//   - grid = 4096 row-blocks x 3 hp-groups, siblings adjacent in bid so the
//     3x feats reads stay L3-time-coherent.
//  wk / gk / fallback unchanged (accuracy-verified R7/R8).

#define KH 24
#define SS 16384
#define VV 8
#define DD 256
#define NROW 131072
#define NE (KH * SS)

typedef __attribute__((ext_vector_type(8))) short s16x8;
typedef __attribute__((ext_vector_type(4))) float f32x4;
typedef __attribute__((ext_vector_type(4))) unsigned int u32x4;

__device__ __forceinline__ unsigned short rne_bf16(float f) {
    unsigned u = __builtin_bit_cast(unsigned, f);
    unsigned r = u + 0x7FFFu + ((u >> 16) & 1u);
    return (unsigned short)(r >> 16);
}
__device__ __forceinline__ float bf16f(unsigned short h) {
    unsigned u = ((unsigned)h) << 16;
    return __builtin_bit_cast(float, u);
}

template <int CTRL>
__device__ __forceinline__ float dpp_mov(float x) {
    int xi = __builtin_bit_cast(int, x);
    int r = __builtin_amdgcn_update_dpp(xi, xi, CTRL, 0xF, 0xF, false);
    return __builtin_bit_cast(float, r);
}

// ---- wk: split W into bf16 hi/lo in MFMA B-fragment order (R7-verified) ----
// whi/wlo[((hp*8+kb)*64+lane)*8+j]: k = kb*32+(lane>>4)*8+j, n = lane&15,
// head = hp*2+(n>>3), v = n&7.
__global__ __launch_bounds__(256) void wk_kernel(
    const float* __restrict__ head_w, unsigned short* __restrict__ whi,
    unsigned short* __restrict__ wlo)
{
    const int idx = blockIdx.x * 256 + threadIdx.x;     // 0..49151
    const int j = idx & 7, lane = (idx >> 3) & 63;
    const int kb = (idx >> 9) & 7, hp = idx >> 12;
    const int head = hp * 2 + ((lane & 15) >> 3);
    const int v = lane & 7;
    const int k = kb * 32 + (lane >> 4) * 8 + j;
    const float f = head_w[((size_t)head * DD + k) * VV + v];
    const unsigned short hi = rne_bf16(f);
    whi[idx] = hi;
    wlo[idx] = rne_bf16(f - bf16f(hi));
}

// ---- mks: 32-row A-tile in LDS (hi/lo, swizzled); wave owns one hp --------
__global__ __launch_bounds__(256, 4) void mks_kernel(
    const float* __restrict__ feats,
    const unsigned short* __restrict__ whi,
    const unsigned short* __restrict__ wlo,
    float* __restrict__ logits)
{
    const int tid  = threadIdx.x;
    const int wave = tid >> 6;
    const int lane = tid & 63;
    const int bid  = blockIdx.x;
    const int rb   = bid / 3;            // row-block 0..4095
    const int hpg  = bid - rb * 3;       // 0..2
    const int hp   = hpg * 4 + wave;     // this wave's head-pair
    const int r0   = rb * 32;

    // LDS: A as bf16 planes, 32 rows x 256 k, swizzled byte^=(row&7)<<4.
    __shared__ unsigned short Ahi[32 * 256];   // 16KB
    __shared__ unsigned short Alo[32 * 256];   // 16KB

    // ---- Stage A once (cooperative): thread t -> row t>>3, chunk-pair t&7.
    {
        const int row = tid >> 3;
        const int c8  = tid & 7;
        const float* src = feats + (size_t)(r0 + row) * DD + c8 * 8;
        const unsigned sw = ((unsigned)(row & 7)) << 4;
#pragma unroll
        for (int i = 0; i < 4; ++i) {
            const float4 p = *(const float4*)(src + i * 64);
            const float4 q = *(const float4*)(src + i * 64 + 4);
            const float fv[8] = {p.x, p.y, p.z, p.w, q.x, q.y, q.z, q.w};
            s16x8 h, l;
#pragma unroll
            for (int j = 0; j < 8; ++j) {
                const unsigned short hi = rne_bf16(fv[j]);
                h[j] = (short)hi;
                l[j] = (short)rne_bf16(fv[j] - bf16f(hi));
            }
            const unsigned byteoff = ((unsigned)(row * 512 + c8 * 16 + i * 128)) ^ sw;
            *(s16x8*)((char*)Ahi + byteoff) = h;
            *(s16x8*)((char*)Alo + byteoff) = l;
        }
    }

    // ---- B fragments register-resident (asm-pinned). 16B/lane per plane/kb.
    s16x8 Bh[8], Bl[8];
#pragma unroll
    for (int kb = 0; kb < 8; ++kb) {
        Bh[kb] = *(const s16x8*)(whi + (((size_t)hp * 8 + kb) * 64 + lane) * 8);
        Bl[kb] = *(const s16x8*)(wlo + (((size_t)hp * 8 + kb) * 64 + lane) * 8);
        u32x4 ph = __builtin_bit_cast(u32x4, Bh[kb]);
        u32x4 pl = __builtin_bit_cast(u32x4, Bl[kb]);
        asm volatile("" : "+v"(ph), "+v"(pl));
        Bh[kb] = __builtin_bit_cast(s16x8, ph);
        Bl[kb] = __builtin_bit_cast(s16x8, pl);
    }

    __syncthreads();    // the ONLY barrier

    const int m  = lane & 15;
    const int kq = lane >> 4;

#pragma unroll
    for (int mt = 0; mt < 2; ++mt) {
        // A-frag LDS address: row = mt*16 + m, k = kb*32 + kq*8
        const int arow = mt * 16 + m;
        const unsigned abase = ((unsigned)(arow * 512 + kq * 16)) ^ (((unsigned)(arow & 7)) << 4);

        f32x4 c0 = {0.f, 0.f, 0.f, 0.f};
        f32x4 c1 = {0.f, 0.f, 0.f, 0.f};
#pragma unroll
        for (int kb = 0; kb < 8; kb += 2) {
            const s16x8 ah0 = *(const s16x8*)((const char*)Ahi + (abase ^ (unsigned)(kb * 64)));
            const s16x8 al0 = *(const s16x8*)((const char*)Alo + (abase ^ (unsigned)(kb * 64)));
            const s16x8 ah1 = *(const s16x8*)((const char*)Ahi + (abase ^ (unsigned)((kb + 1) * 64)));
            const s16x8 al1 = *(const s16x8*)((const char*)Alo + (abase ^ (unsigned)((kb + 1) * 64)));
            c0 = __builtin_amdgcn_mfma_f32_16x16x32_bf16(ah0, Bh[kb], c0, 0, 0, 0);
            c1 = __builtin_amdgcn_mfma_f32_16x16x32_bf16(ah1, Bh[kb + 1], c1, 0, 0, 0);
            c0 = __builtin_amdgcn_mfma_f32_16x16x32_bf16(al0, Bh[kb], c0, 0, 0, 0);
            c1 = __builtin_amdgcn_mfma_f32_16x16x32_bf16(al1, Bh[kb + 1], c1, 0, 0, 0);
            c0 = __builtin_amdgcn_mfma_f32_16x16x32_bf16(ah0, Bl[kb], c0, 0, 0, 0);
            c1 = __builtin_amdgcn_mfma_f32_16x16x32_bf16(ah1, Bl[kb + 1], c1, 0, 0, 0);
        }
        const f32x4 c = c0 + c1;

        // D[row=kq*4+rg][col=m] -> logits[hp][r0 + mt*16 + kq*4 + rg][m]
        float* Lp = logits + ((size_t)hp * NROW + (r0 + mt * 16 + kq * 4)) * 16 + m;
#pragma unroll
        for (int rg = 0; rg < 4; ++rg)
            Lp[(size_t)rg * 16] = c[rg];
    }
    // note: kb*64 lives in bits >=6 except bit6; XOR with abase (bits 4-6
    // carry swizzle) is used instead of add so the swizzled bit6 is
    // preserved: (row-swizzle affects bits 4-6; kb*64 bits 6-8). Using ^ is
    // safe because abase bit6 = ((arow&7)<<4 bit6) ^ (kq*16 bit6=0); adding
    // kb*64 could carry -- XOR keeps the mapping the exact involution the
    // writer used: byte(row,k) ^ sw with byte = row*512 + k*2.
}

// ---- gk: out[t] = logits[(hp*NROW+row)*16 + half*8 + v] + bias ------------
__global__ __launch_bounds__(256) void gk_kernel(
    const float* __restrict__ logits,
    const int* __restrict__ mask_idx,
    const float* __restrict__ head_b,
    float* __restrict__ out)
{
    const int t = blockIdx.x * 256 + threadIdx.x;       // 0 .. NE*8-1
    const int e = t >> 3;                               // (k,s) entry
    const int v = t & 7;
    const int k = e >> 14;
    const unsigned row = (unsigned)mask_idx[e];
    const int hp = k >> 1, half = k & 1;
    out[t] = logits[((size_t)hp * NROW + row) * 16 + half * 8 + v]
           + head_b[k * VV + v];
}

// ---------------- Fallback (verified R3) if workspace too small ------------
__global__ __launch_bounds__(256) void attr_decoder_fallback(
    const float* __restrict__ feats, const int* __restrict__ mask_idx,
    const float* __restrict__ head_w, const float* __restrict__ head_b,
    float* __restrict__ out)
{
    const int lane  = threadIdx.x & 63;
    const int wv    = __builtin_amdgcn_readfirstlane(threadIdx.x >> 6);
    const int k     = blockIdx.x >> 7;
    const int chunk = blockIdx.x & 127;
    const int lb    = lane & 7;

    const float* Wk = head_w + (size_t)k * (DD * VV);
    float w[4][8];
    {
        const bool q0 = (lane & 1) != 0;
        const bool q1 = (lane & 2) != 0;
        const bool q2 = (lane & 4) != 0;
#pragma unroll
        for (int t = 0; t < 4; ++t) {
            const float4 a = *(const float4*)(Wk + (lane * 4 + t) * VV);
            const float4 b = *(const float4*)(Wk + (lane * 4 + t) * VV + 4);
            const float x[8] = {a.x, a.y, a.z, a.w, b.x, b.y, b.z, b.w};
            float y[8], z[8];
#pragma unroll
            for (int j = 0; j < 8; ++j) y[j] = q0 ? x[j ^ 1] : x[j];
#pragma unroll
            for (int j = 0; j < 8; ++j) z[j] = q1 ? y[j ^ 2] : y[j];
#pragma unroll
            for (int j = 0; j < 8; ++j) w[t][j] = q2 ? z[j ^ 4] : z[j];
        }
    }
    const float bias = head_b[k * VV + lb];

    const char* fb = (const char*)feats;
    const int s_base = chunk * 128 + wv * 32;
    const int* mi = mask_idx + k * SS + s_base;
    float* outp = out + ((size_t)k * SS + s_base) * VV;
    const int vo = lane << 4;

    int4 rows = *(const int4*)mi;
    int r0 = __builtin_amdgcn_readfirstlane(rows.x);
    int r1 = __builtin_amdgcn_readfirstlane(rows.y);
    int r2 = __builtin_amdgcn_readfirstlane(rows.z);
    int r3 = __builtin_amdgcn_readfirstlane(rows.w);

    for (int i = 0; i < 32; i += 4) {
        const float4 f0 = *(const float4*)(fb + (((size_t)(unsigned)r0) << 10) + vo);
        const float4 f1 = *(const float4*)(fb + (((size_t)(unsigned)r1) << 10) + vo);
        const float4 f2 = *(const float4*)(fb + (((size_t)(unsigned)r2) << 10) + vo);
        const float4 f3 = *(const float4*)(fb + (((size_t)(unsigned)r3) << 10) + vo);
        if (i < 28) rows = *(const int4*)(mi + i + 4);

        float r[4];
        const float4 f[4] = {f0, f1, f2, f3};
#pragma unroll
        for (int u = 0; u < 4; ++u) {
            float acc[8];
#pragma unroll
            for (int v = 0; v < 8; ++v) {
                acc[v] = f[u].x * w[0][v];
                acc[v] = fmaf(f[u].y, w[1][v], acc[v]);
                acc[v] = fmaf(f[u].z, w[2][v], acc[v]);
                acc[v] = fmaf(f[u].w, w[3][v], acc[v]);
            }
            const float a40 = acc[0] + dpp_mov<0xB1>(acc[1]);
            const float a41 = acc[2] + dpp_mov<0xB1>(acc[3]);
            const float a42 = acc[4] + dpp_mov<0xB1>(acc[5]);
            const float a43 = acc[6] + dpp_mov<0xB1>(acc[7]);
            const float a20 = a40 + dpp_mov<0x4E>(a41);
            const float a21 = a42 + dpp_mov<0x4E>(a43);
            r[u] = a20 + __shfl_xor(a21, 4, 64);
        }
        r0 = __builtin_amdgcn_readfirstlane(rows.x);
        r1 = __builtin_amdgcn_readfirstlane(rows.y);
        r2 = __builtin_amdgcn_readfirstlane(rows.z);
        r3 = __builtin_amdgcn_readfirstlane(rows.w);

        const bool b3 = (lane & 8) != 0;
        const bool b4 = (lane & 16) != 0;
        const float t0 = (b3 ? r[1] : r[0]) + dpp_mov<0x128>(b3 ? r[0] : r[1]);
        const float t1 = (b3 ? r[3] : r[2]) + dpp_mov<0x128>(b3 ? r[2] : r[3]);
        float va = (b4 ? t1 : t0) + __shfl_xor(b4 ? t0 : t1, 16, 64);
        va += __shfl_xor(va, 32, 64);
        if (lane < 32) outp[i * VV + lane] = va + bias;
    }
}

extern "C" void kernel_launch(void* const* d_in, const int* in_sizes, int n_in,
                              void* d_out, int out_size, void* d_ws, size_t ws_size,
                              hipStream_t stream) {
    const float* feats    = (const float*)d_in[1];
    const int*   mask_idx = (const int*)  d_in[2];
    const float* head_w   = (const float*)d_in[3];
    const float* head_b   = (const float*)d_in[4];
    float* out = (float*)d_out;

    // Workspace layout (bytes):
    //   logits @ 0         : 12*131072*16*4 = 100663296
    //   whi    @ 100663296 : 49152*2        = 98304
    //   wlo    @ 100761600 : 98304
    const size_t need = 100663296u + 2u * 98304u;
    if (d_ws != nullptr && ws_size >= need) {
        char* ws = (char*)d_ws;
        float* logits = (float*)ws;
        unsigned short* whi = (unsigned short*)(ws + 100663296u);
        unsigned short* wlo = (unsigned short*)(ws + 100761600u);

        wk_kernel<<<dim3(192),        dim3(256), 0, stream>>>(head_w, whi, wlo);
        mks_kernel<<<dim3(4096 * 3),  dim3(256), 0, stream>>>(feats, whi, wlo, logits);
        gk_kernel<<<dim3(NE * VV / 256), dim3(256), 0, stream>>>(
            logits, mask_idx, head_b, out);
    } else {
        attr_decoder_fallback<<<dim3(KH * 128), dim3(256), 0, stream>>>(
            feats, mask_idx, head_w, head_b, out);
    }
}